// Round 17
// baseline (469.157 us; speedup 1.0000x reference)
//
#include <hip/hip_runtime.h>

#define HDIM 64
#define STEPS 3

// ---------------- embed: x[i] = emb[tokens[i]] ----------------
__global__ __launch_bounds__(256) void k_embed(const int* __restrict__ tokens,
                                               const float* __restrict__ emb,
                                               float* __restrict__ x, int n) {
  int i = blockIdx.x * 256 + threadIdx.x;
  if (i < n * HDIM) {
    int node = i >> 6;
    int h = i & 63;
    x[i] = emb[tokens[node] * HDIM + h];
  }
}

// ---------------- one-time (fused): whT transpose + wc = W_s @ w_ih^T ----------------
__global__ __launch_bounds__(256) void k_prep(const float* __restrict__ W,
                                              const float* __restrict__ w_ih,
                                              const float* __restrict__ w_hh,
                                              float* __restrict__ wc,
                                              float* __restrict__ whT) {
  int o = blockIdx.x * 256 + threadIdx.x;
  const int per = HDIM * 3 * HDIM;  // 12288
  if (o < per) {
    int k = o / (3 * HDIM);
    int j = o % (3 * HDIM);
    whT[o] = w_hh[j * HDIM + k];
  }
  if (o < STEPS * per) {
    int s = o / per;
    int rem = o - s * per;
    int k = rem / (3 * HDIM);
    int j = rem - k * (3 * HDIM);
    const float4* a4 = (const float4*)(W + (size_t)s * HDIM * HDIM + (size_t)k * HDIM);
    const float4* b4 = (const float4*)(w_ih + (size_t)j * HDIM);
    float acc = 0.f;
#pragma unroll
    for (int q = 0; q < HDIM / 4; ++q) {
      float4 a = a4[q];
      float4 b = b4[q];
      acc = fmaf(a.x, b.x, acc);
      acc = fmaf(a.y, b.y, acc);
      acc = fmaf(a.z, b.z, acc);
      acc = fmaf(a.w, b.w, acc);
    }
    wc[o] = acc;
  }
}

// ---------------- CSR build ----------------
__global__ __launch_bounds__(256) void k_hist(const int* __restrict__ dsts,
                                              int* __restrict__ deg, int ne) {
  int e = blockIdx.x * 256 + threadIdx.x;
  if (e < ne) atomicAdd(&deg[dsts[e]], 1);
}

__global__ __launch_bounds__(256) void k_scan1(const int* __restrict__ deg,
                                               int* __restrict__ bsum, int n) {
  __shared__ int s[256];
  const int tid = threadIdx.x;
  int i = blockIdx.x * 256 + tid;
  s[tid] = (i < n) ? deg[i] : 0;
  __syncthreads();
  for (int off = 128; off > 0; off >>= 1) {
    if (tid < off) s[tid] += s[tid + off];
    __syncthreads();
  }
  if (tid == 0) bsum[blockIdx.x] = s[0];
}

__global__ __launch_bounds__(1024) void k_scan2(int* __restrict__ bsum, int nb) {
  __shared__ int s[1024];
  const int tid = threadIdx.x;
  int carry = 0;
  for (int base = 0; base < nb; base += 1024) {
    int i = base + tid;
    int v = (i < nb) ? bsum[i] : 0;
    s[tid] = v;
    __syncthreads();
    for (int off = 1; off < 1024; off <<= 1) {
      int t = (tid >= off) ? s[tid - off] : 0;
      __syncthreads();
      s[tid] += t;
      __syncthreads();
    }
    if (i < nb) bsum[i] = carry + s[tid] - v;  // exclusive
    carry += s[1023];
    __syncthreads();
  }
}

__global__ __launch_bounds__(256) void k_scan3(const int* __restrict__ deg,
                                               const int* __restrict__ bsum,
                                               int* __restrict__ rowptr,
                                               int* __restrict__ cursor, int n) {
  __shared__ int s[256];
  const int tid = threadIdx.x;
  int i = blockIdx.x * 256 + tid;
  int v = (i < n) ? deg[i] : 0;
  s[tid] = v;
  __syncthreads();
  for (int off = 1; off < 256; off <<= 1) {
    int t = (tid >= off) ? s[tid - off] : 0;
    __syncthreads();
    s[tid] += t;
    __syncthreads();
  }
  int excl = bsum[blockIdx.x] + s[tid] - v;
  if (i < n) {
    rowptr[i] = excl;
    cursor[i] = excl;
    if (i == n - 1) rowptr[n] = excl + v;
  }
}

__global__ __launch_bounds__(256) void k_fill(const int* __restrict__ srcs,
                                              const int* __restrict__ dsts,
                                              int* __restrict__ cursor,
                                              int* __restrict__ eidx, int ne) {
  int e = blockIdx.x * 256 + threadIdx.x;
  if (e < ne) {
    int d = dsts[e];
    int p = atomicAdd(&cursor[d], 1);
    eidx[p] = srcs[e];
  }
}

// ---------------- FUSED gather + GRU: xout = GRU(sum_nbrs(xin) @ Wc, xin) ----------------
// Occupancy lever: wiT LDS holds only r,z gates (32KB); n-gate input weights
// (win) read from global like whT (4 global streams; R14's failure was 6).
// LDS = 32 + abuf 8 + hbuf 8 = 48KB -> 3 blocks/CU = 24 waves (+50% vs 16)
// IF VGPR stays <=64 (R11 body was 52; fallback = current perf, not a cliff).
// Gather is the R11 4-stream float4 form (fastest of 3 measured variants).
__global__ __launch_bounds__(512, 2) void k_fgru(const int* __restrict__ rowptr,
                                                 const int* __restrict__ eidx,
                                                 const float4* __restrict__ xin4,
                                                 const float* __restrict__ xin,
                                                 float* __restrict__ xout,
                                                 const float* __restrict__ wc_g,
                                                 const float* __restrict__ whT_g,
                                                 const float* __restrict__ b_ih,
                                                 const float* __restrict__ b_hh,
                                                 int n) {
  __shared__ float wiT2[HDIM * 2 * HDIM];  // 32KB: [k][gate(r,z)*64+lane]
  __shared__ float abuf[8][4][HDIM];       // 8KB, wave-private gather result
  __shared__ float hbuf[8][4][HDIM];       // 8KB, wave-private h rows
  for (int t = threadIdx.x; t < HDIM * 2 * HDIM; t += 512) {
    int k = t >> 7;
    int j = t & 127;
    wiT2[t] = wc_g[k * 192 + j];
  }
  __syncthreads();

  const int lane = threadIdx.x & 63;
  const int wid = threadIdx.x >> 6;  // 0..7
  const int NG = (n + 3) >> 2;
  int g = blockIdx.x * 8 + wid;
  if (g >= NG) return;

  const int node0 = g * 4;
  const int grp = lane >> 4;    // edge stream 0..3
  const int cl = lane & 15;     // float4 channel chunk

  // --- gather phase: 4 nodes of this wave (R11 proven form) ---
#pragma unroll
  for (int i = 0; i < 4; ++i) {
    int node = node0 + i;
    float4 acc = make_float4(0.f, 0.f, 0.f, 0.f);
    if (node < n) {
      const int lo = rowptr[node], hi = rowptr[node + 1];
      int e = lo + grp;
      for (; e + 4 < hi; e += 8) {
        int s0 = eidx[e];
        int s1 = eidx[e + 4];
        float4 v0 = xin4[(size_t)s0 * 16 + cl];
        float4 v1 = xin4[(size_t)s1 * 16 + cl];
        acc.x += v0.x + v1.x;
        acc.y += v0.y + v1.y;
        acc.z += v0.z + v1.z;
        acc.w += v0.w + v1.w;
      }
      if (e < hi) {
        int s0 = eidx[e];
        float4 v0 = xin4[(size_t)s0 * 16 + cl];
        acc.x += v0.x; acc.y += v0.y; acc.z += v0.z; acc.w += v0.w;
      }
    }
#pragma unroll
    for (int off = 16; off < 64; off <<= 1) {
      acc.x += __shfl_xor(acc.x, off);
      acc.y += __shfl_xor(acc.y, off);
      acc.z += __shfl_xor(acc.z, off);
      acc.w += __shfl_xor(acc.w, off);
    }
    if (grp == 0) *((float4*)&abuf[wid][i][cl * 4]) = acc;
  }

  // --- own rows ---
  float xv[4];
#pragma unroll
  for (int i = 0; i < 4; ++i) {
    int node = node0 + i;
    xv[i] = (node < n) ? xin[(size_t)node * HDIM + lane] : 0.f;
    hbuf[wid][i][lane] = xv[i];
  }

  const float Br = b_ih[lane] + b_hh[lane];
  const float Bz = b_ih[HDIM + lane] + b_hh[HDIM + lane];
  const float Bin = b_ih[2 * HDIM + lane];
  const float Bhn = b_hh[2 * HDIM + lane];

  float ar[4] = {0, 0, 0, 0}, az[4] = {0, 0, 0, 0}, an[4] = {0, 0, 0, 0};
  float hr[4] = {0, 0, 0, 0}, hz[4] = {0, 0, 0, 0}, hn[4] = {0, 0, 0, 0};

#pragma unroll 1
  for (int kk = 0; kk < HDIM; kk += 4) {
    float wr[4], wz[4], wn[4], vr[4], vz[4], vn[4];
#pragma unroll
    for (int q = 0; q < 4; ++q) {
      int k = kk + q;
      wr[q] = wiT2[k * 128 + lane];
      wz[q] = wiT2[k * 128 + 64 + lane];
      wn[q] = wc_g[k * 192 + 128 + lane];   // global (L2-hot)
      vr[q] = whT_g[k * 192 + lane];
      vz[q] = whT_g[k * 192 + 64 + lane];
      vn[q] = whT_g[k * 192 + 128 + lane];
    }
#pragma unroll
    for (int i = 0; i < 4; ++i) {
      const float4 a4 = *(const float4*)&abuf[wid][i][kk];  // uniform, broadcast
      const float4 h4 = *(const float4*)&hbuf[wid][i][kk];
      ar[i] = fmaf(a4.x, wr[0], ar[i]); az[i] = fmaf(a4.x, wz[0], az[i]); an[i] = fmaf(a4.x, wn[0], an[i]);
      hr[i] = fmaf(h4.x, vr[0], hr[i]); hz[i] = fmaf(h4.x, vz[0], hz[i]); hn[i] = fmaf(h4.x, vn[0], hn[i]);
      ar[i] = fmaf(a4.y, wr[1], ar[i]); az[i] = fmaf(a4.y, wz[1], az[i]); an[i] = fmaf(a4.y, wn[1], an[i]);
      hr[i] = fmaf(h4.y, vr[1], hr[i]); hz[i] = fmaf(h4.y, vz[1], hz[i]); hn[i] = fmaf(h4.y, vn[1], hn[i]);
      ar[i] = fmaf(a4.z, wr[2], ar[i]); az[i] = fmaf(a4.z, wz[2], az[i]); an[i] = fmaf(a4.z, wn[2], an[i]);
      hr[i] = fmaf(h4.z, vr[2], hr[i]); hz[i] = fmaf(h4.z, vz[2], hz[i]); hn[i] = fmaf(h4.z, vn[2], hn[i]);
      ar[i] = fmaf(a4.w, wr[3], ar[i]); az[i] = fmaf(a4.w, wz[3], az[i]); an[i] = fmaf(a4.w, wn[3], an[i]);
      hr[i] = fmaf(h4.w, vr[3], hr[i]); hz[i] = fmaf(h4.w, vz[3], hz[i]); hn[i] = fmaf(h4.w, vn[3], hn[i]);
    }
  }

#pragma unroll
  for (int i = 0; i < 4; ++i) {
    int node = node0 + i;
    if (node < n) {
      float r = 1.f / (1.f + __expf(-(ar[i] + hr[i] + Br)));
      float z = 1.f / (1.f + __expf(-(az[i] + hz[i] + Bz)));
      float nn = tanhf((an[i] + Bin) + r * (hn[i] + Bhn));
      xout[(size_t)node * HDIM + lane] = (1.f - z) * nn + z * xv[i];
    }
  }
}

// ---------------- per-graph mean pool of relu(x); batch sorted ----------------
__device__ __forceinline__ int lower_bound_i(const int* __restrict__ a, int n, int v) {
  int lo = 0, hi = n;
  while (lo < hi) {
    int mid = (lo + hi) >> 1;
    if (a[mid] < v) lo = mid + 1; else hi = mid;
  }
  return lo;
}

__global__ __launch_bounds__(256) void k_pool(const float* __restrict__ x,
                                              const int* __restrict__ batch,
                                              float* __restrict__ pooled,
                                              int n) {
  int g = blockIdx.x;
  int lo = lower_bound_i(batch, n, g);
  int hi = lower_bound_i(batch, n, g + 1);
  const int lane = threadIdx.x & 63;
  const int w = threadIdx.x >> 6;  // 0..3
  float acc = 0.f;
  for (int i = lo + w; i < hi; i += 4) {
    acc += fmaxf(x[i * HDIM + lane], 0.f);
  }
  __shared__ float red[4][HDIM];
  red[w][lane] = acc;
  __syncthreads();
  if (w == 0) {
    float s = red[0][lane] + red[1][lane] + red[2][lane] + red[3][lane];
    float cnt = (float)(hi - lo);
    pooled[g * HDIM + lane] = s / fmaxf(cnt, 1.f);
  }
}

// ---------------- head ----------------
__global__ __launch_bounds__(256) void k_head(const float* __restrict__ pooled,
                                              const float* __restrict__ lin1_w,
                                              const float* __restrict__ lin1_b,
                                              const float* __restrict__ lout_w,
                                              const float* __restrict__ lout_b,
                                              float* __restrict__ out, int G) {
  __shared__ float P[128 * HDIM];
  __shared__ float W1T[HDIM * HDIM];
  __shared__ float H1[128 * HDIM];
  for (int t = threadIdx.x; t < G * HDIM; t += 256) P[t] = pooled[t];
  for (int t = threadIdx.x; t < HDIM * HDIM; t += 256) {
    int j = t & 63, k = t >> 6;
    W1T[k * HDIM + j] = lin1_w[j * HDIM + k];
  }
  __syncthreads();
  for (int idx = threadIdx.x; idx < G * HDIM; idx += 256) {
    int g = idx >> 6, j = idx & 63;
    float acc = lin1_b[j];
#pragma unroll
    for (int k = 0; k < HDIM; ++k) acc = fmaf(P[g * HDIM + k], W1T[k * HDIM + j], acc);
    H1[idx] = fmaxf(acc, 0.f);
  }
  __syncthreads();
  for (int idx = threadIdx.x; idx < G * 2; idx += 256) {
    int g = idx >> 1, c = idx & 1;
    float acc = lout_b[c];
#pragma unroll
    for (int j = 0; j < HDIM; ++j) acc = fmaf(H1[g * HDIM + j], lout_w[c * HDIM + j], acc);
    out[idx] = acc;
  }
}

extern "C" void kernel_launch(void* const* d_in, const int* in_sizes, int n_in,
                              void* d_out, int out_size, void* d_ws, size_t ws_size,
                              hipStream_t stream) {
  const int* tokens   = (const int*)d_in[0];
  const int* edge_idx = (const int*)d_in[1];
  const int* batch    = (const int*)d_in[2];
  const float* emb    = (const float*)d_in[3];
  const float* ggnn_w = (const float*)d_in[4];
  const float* w_ih   = (const float*)d_in[5];
  const float* w_hh   = (const float*)d_in[6];
  const float* b_ih   = (const float*)d_in[7];
  const float* b_hh   = (const float*)d_in[8];
  const float* lin1_w = (const float*)d_in[9];
  const float* lin1_b = (const float*)d_in[10];
  const float* lout_w = (const float*)d_in[11];
  const float* lout_b = (const float*)d_in[12];

  const int N = in_sizes[0];
  const int E = in_sizes[1] / 2;
  const int G = out_size / 2;

  const int* srcs = edge_idx;
  const int* dsts = edge_idx + E;

  char* ws = (char*)d_ws;
  size_t off = 0;
  auto take = [&](size_t nbytes) -> char* {
    char* p = ws + off;
    off += (nbytes + 255) & ~(size_t)255;
    return p;
  };
  size_t rowBytes = (size_t)N * HDIM * sizeof(float);
  const int nb256 = (N + 255) / 256;
  float* xA     = (float*)take(rowBytes);
  float* xB     = (float*)take(rowBytes);
  float* pooled = (float*)take((size_t)G * HDIM * sizeof(float));
  float* whT_g  = (float*)take(HDIM * 3 * HDIM * sizeof(float));
  float* wc_g   = (float*)take((size_t)STEPS * HDIM * 3 * HDIM * sizeof(float));
  int* rowptr   = (int*)take((size_t)(N + 1) * sizeof(int));
  int* cursor   = (int*)take((size_t)N * sizeof(int));  // also used as deg
  int* bsum     = (int*)take((size_t)nb256 * sizeof(int));
  int* eidx     = (int*)take((size_t)E * sizeof(int));

  // --- one-time precompute: whT + combined input weights (fused), CSR by dst ---
  {
    const int total = STEPS * HDIM * 3 * HDIM;
    k_prep<<<(total + 255) / 256, 256, 0, stream>>>(ggnn_w, w_ih, w_hh, wc_g, whT_g);
  }
  hipMemsetAsync(cursor, 0, (size_t)N * sizeof(int), stream);
  k_hist<<<(E + 255) / 256, 256, 0, stream>>>(dsts, cursor, E);
  k_scan1<<<nb256, 256, 0, stream>>>(cursor, bsum, N);
  k_scan2<<<1, 1024, 0, stream>>>(bsum, nb256);
  k_scan3<<<nb256, 256, 0, stream>>>(cursor, bsum, rowptr, cursor, N);
  k_fill<<<(E + 255) / 256, 256, 0, stream>>>(srcs, dsts, cursor, eidx, E);

  // --- embed ---
  k_embed<<<(N * HDIM + 255) / 256, 256, 0, stream>>>(tokens, emb, xA, N);

  // --- GGNN steps: fused gather+GRU, ping-pong x ---
  const int NG = (N + 3) / 4;
  const int fblocks = (NG + 7) / 8;
  float* xin = xA;
  float* xout = xB;
  for (int s = 0; s < STEPS; ++s) {
    k_fgru<<<fblocks, 512, 0, stream>>>(rowptr, eidx, (const float4*)xin, xin, xout,
                                        wc_g + (size_t)s * HDIM * 3 * HDIM,
                                        whT_g, b_ih, b_hh, N);
    float* tmp = xin; xin = xout; xout = tmp;
  }

  k_pool<<<G, 256, 0, stream>>>(xin, batch, pooled, N);
  k_head<<<1, 256, 0, stream>>>(pooled, lin1_w, lin1_b, lout_w, lout_b,
                                (float*)d_out, G);
}

// Round 18
// 439.550 us; speedup vs baseline: 1.0674x; 1.0674x over previous
//
#include <hip/hip_runtime.h>

#define HDIM 64
#define STEPS 3

// ---------------- embed: x[i] = emb[tokens[i]] ----------------
__global__ __launch_bounds__(256) void k_embed(const int* __restrict__ tokens,
                                               const float* __restrict__ emb,
                                               float* __restrict__ x, int n) {
  int i = blockIdx.x * 256 + threadIdx.x;
  if (i < n * HDIM) {
    int node = i >> 6;
    int h = i & 63;
    x[i] = emb[tokens[node] * HDIM + h];
  }
}

// ---------------- one-time prep: K-major float4 weight layouts ----------------
// wc4[s][kk16][gate][lane][q]  (gate 0=r,1=z,2=n; k = kk16*4+q):
//   = dot(W_s[k][:], w_ih[gate*64+lane][:])
// whT4[kk16][gate][lane][q] = w_hh[gate*64+lane][k]
__global__ __launch_bounds__(256) void k_prep(const float* __restrict__ W,
                                              const float* __restrict__ w_ih,
                                              const float* __restrict__ w_hh,
                                              float* __restrict__ wc,
                                              float* __restrict__ whT) {
  int o = blockIdx.x * 256 + threadIdx.x;
  const int per = HDIM * 3 * HDIM;  // 12288
  if (o >= STEPS * per) return;
  int s = o / per;
  int rem = o - s * per;
  int q = rem & 3;
  int lane = (rem >> 2) & 63;
  int gj = rem >> 8;         // kk16*3+gate
  int gate = gj % 3;
  int kk16 = gj / 3;
  int k = kk16 * 4 + q;
  int j = gate * 64 + lane;
  if (o < per) {
    whT[o] = w_hh[j * HDIM + k];
  }
  const float4* a4 = (const float4*)(W + (size_t)s * HDIM * HDIM + (size_t)k * HDIM);
  const float4* b4 = (const float4*)(w_ih + (size_t)j * HDIM);
  float acc = 0.f;
#pragma unroll
  for (int t = 0; t < HDIM / 4; ++t) {
    float4 a = a4[t];
    float4 b = b4[t];
    acc = fmaf(a.x, b.x, acc);
    acc = fmaf(a.y, b.y, acc);
    acc = fmaf(a.z, b.z, acc);
    acc = fmaf(a.w, b.w, acc);
  }
  wc[o] = acc;
}

// ---------------- CSR build ----------------
__global__ __launch_bounds__(256) void k_hist(const int* __restrict__ dsts,
                                              int* __restrict__ deg, int ne) {
  int e = blockIdx.x * 256 + threadIdx.x;
  if (e < ne) atomicAdd(&deg[dsts[e]], 1);
}

__global__ __launch_bounds__(256) void k_scan1(const int* __restrict__ deg,
                                               int* __restrict__ bsum, int n) {
  __shared__ int s[256];
  const int tid = threadIdx.x;
  int i = blockIdx.x * 256 + tid;
  s[tid] = (i < n) ? deg[i] : 0;
  __syncthreads();
  for (int off = 128; off > 0; off >>= 1) {
    if (tid < off) s[tid] += s[tid + off];
    __syncthreads();
  }
  if (tid == 0) bsum[blockIdx.x] = s[0];
}

__global__ __launch_bounds__(1024) void k_scan2(int* __restrict__ bsum, int nb) {
  __shared__ int s[1024];
  const int tid = threadIdx.x;
  int carry = 0;
  for (int base = 0; base < nb; base += 1024) {
    int i = base + tid;
    int v = (i < nb) ? bsum[i] : 0;
    s[tid] = v;
    __syncthreads();
    for (int off = 1; off < 1024; off <<= 1) {
      int t = (tid >= off) ? s[tid - off] : 0;
      __syncthreads();
      s[tid] += t;
      __syncthreads();
    }
    if (i < nb) bsum[i] = carry + s[tid] - v;  // exclusive
    carry += s[1023];
    __syncthreads();
  }
}

__global__ __launch_bounds__(256) void k_scan3(const int* __restrict__ deg,
                                               const int* __restrict__ bsum,
                                               int* __restrict__ rowptr,
                                               int* __restrict__ cursor, int n) {
  __shared__ int s[256];
  const int tid = threadIdx.x;
  int i = blockIdx.x * 256 + tid;
  int v = (i < n) ? deg[i] : 0;
  s[tid] = v;
  __syncthreads();
  for (int off = 1; off < 256; off <<= 1) {
    int t = (tid >= off) ? s[tid - off] : 0;
    __syncthreads();
    s[tid] += t;
    __syncthreads();
  }
  int excl = bsum[blockIdx.x] + s[tid] - v;
  if (i < n) {
    rowptr[i] = excl;
    cursor[i] = excl;
    if (i == n - 1) rowptr[n] = excl + v;
  }
}

__global__ __launch_bounds__(256) void k_fill(const int* __restrict__ srcs,
                                              const int* __restrict__ dsts,
                                              int* __restrict__ cursor,
                                              int* __restrict__ eidx, int ne) {
  int e = blockIdx.x * 256 + threadIdx.x;
  if (e < ne) {
    int d = dsts[e];
    int p = atomicAdd(&cursor[d], 1);
    eidx[p] = srcs[e];
  }
}

// ---------------- FUSED gather + GRU: xout = GRU(sum_nbrs(xin) @ Wc, xin) ----------------
// R11 split (all wc gates in LDS 48KB, whT global) + K-major float4 weights:
// per 4-k block, 3 ds_read_b128 + 3 coalesced global_dwordx4 replace 32 scalar
// loads -> 4x fewer VMEM/LDS weight ops and 4x less address VALU. FMA order
// preserved exactly (k-ascending) = bit-identical math to R11.
__global__ __launch_bounds__(512, 2) void k_fgru(const int* __restrict__ rowptr,
                                                 const int* __restrict__ eidx,
                                                 const float4* __restrict__ xin4,
                                                 const float* __restrict__ xin,
                                                 float* __restrict__ xout,
                                                 const float* __restrict__ wc_g,
                                                 const float4* __restrict__ wh4,
                                                 const float* __restrict__ b_ih,
                                                 const float* __restrict__ b_hh,
                                                 int n) {
  __shared__ float wiT[HDIM * 3 * HDIM];   // 48KB, K-major float4 layout (copy of wc_g)
  __shared__ float abuf[8][4][HDIM];       // 8KB, wave-private gather result
  __shared__ float hbuf[8][4][HDIM];       // 8KB, wave-private h rows
  for (int t = threadIdx.x; t < HDIM * 3 * HDIM; t += 512) wiT[t] = wc_g[t];
  __syncthreads();

  const int lane = threadIdx.x & 63;
  const int wid = threadIdx.x >> 6;  // 0..7
  const int NG = (n + 3) >> 2;
  int g = blockIdx.x * 8 + wid;
  if (g >= NG) return;

  const int node0 = g * 4;
  const int grp = lane >> 4;    // edge stream 0..3
  const int cl = lane & 15;     // float4 channel chunk

  // --- gather phase: 4 nodes of this wave (R11 proven form) ---
#pragma unroll
  for (int i = 0; i < 4; ++i) {
    int node = node0 + i;
    float4 acc = make_float4(0.f, 0.f, 0.f, 0.f);
    if (node < n) {
      const int lo = rowptr[node], hi = rowptr[node + 1];
      int e = lo + grp;
      for (; e + 4 < hi; e += 8) {
        int s0 = eidx[e];
        int s1 = eidx[e + 4];
        float4 v0 = xin4[(size_t)s0 * 16 + cl];
        float4 v1 = xin4[(size_t)s1 * 16 + cl];
        acc.x += v0.x + v1.x;
        acc.y += v0.y + v1.y;
        acc.z += v0.z + v1.z;
        acc.w += v0.w + v1.w;
      }
      if (e < hi) {
        int s0 = eidx[e];
        float4 v0 = xin4[(size_t)s0 * 16 + cl];
        acc.x += v0.x; acc.y += v0.y; acc.z += v0.z; acc.w += v0.w;
      }
    }
#pragma unroll
    for (int off = 16; off < 64; off <<= 1) {
      acc.x += __shfl_xor(acc.x, off);
      acc.y += __shfl_xor(acc.y, off);
      acc.z += __shfl_xor(acc.z, off);
      acc.w += __shfl_xor(acc.w, off);
    }
    if (grp == 0) *((float4*)&abuf[wid][i][cl * 4]) = acc;
  }

  // --- own rows ---
  float xv[4];
#pragma unroll
  for (int i = 0; i < 4; ++i) {
    int node = node0 + i;
    xv[i] = (node < n) ? xin[(size_t)node * HDIM + lane] : 0.f;
    hbuf[wid][i][lane] = xv[i];
  }

  const float Br = b_ih[lane] + b_hh[lane];
  const float Bz = b_ih[HDIM + lane] + b_hh[HDIM + lane];
  const float Bin = b_ih[2 * HDIM + lane];
  const float Bhn = b_hh[2 * HDIM + lane];

  float ar[4] = {0, 0, 0, 0}, az[4] = {0, 0, 0, 0}, an[4] = {0, 0, 0, 0};
  float hr[4] = {0, 0, 0, 0}, hz[4] = {0, 0, 0, 0}, hn[4] = {0, 0, 0, 0};

#pragma unroll 1
  for (int kk16 = 0; kk16 < 16; ++kk16) {
    const float4 wr4 = *(const float4*)&wiT[(((kk16 * 3 + 0) * 64) + lane) * 4];
    const float4 wz4 = *(const float4*)&wiT[(((kk16 * 3 + 1) * 64) + lane) * 4];
    const float4 wn4 = *(const float4*)&wiT[(((kk16 * 3 + 2) * 64) + lane) * 4];
    const float4 vr4 = wh4[(kk16 * 3 + 0) * 64 + lane];
    const float4 vz4 = wh4[(kk16 * 3 + 1) * 64 + lane];
    const float4 vn4 = wh4[(kk16 * 3 + 2) * 64 + lane];
#pragma unroll
    for (int i = 0; i < 4; ++i) {
      const float4 a4 = *(const float4*)&abuf[wid][i][kk16 * 4];  // uniform, broadcast
      const float4 h4 = *(const float4*)&hbuf[wid][i][kk16 * 4];
      ar[i] = fmaf(a4.x, wr4.x, ar[i]); az[i] = fmaf(a4.x, wz4.x, az[i]); an[i] = fmaf(a4.x, wn4.x, an[i]);
      hr[i] = fmaf(h4.x, vr4.x, hr[i]); hz[i] = fmaf(h4.x, vz4.x, hz[i]); hn[i] = fmaf(h4.x, vn4.x, hn[i]);
      ar[i] = fmaf(a4.y, wr4.y, ar[i]); az[i] = fmaf(a4.y, wz4.y, az[i]); an[i] = fmaf(a4.y, wn4.y, an[i]);
      hr[i] = fmaf(h4.y, vr4.y, hr[i]); hz[i] = fmaf(h4.y, vz4.y, hz[i]); hn[i] = fmaf(h4.y, vn4.y, hn[i]);
      ar[i] = fmaf(a4.z, wr4.z, ar[i]); az[i] = fmaf(a4.z, wz4.z, az[i]); an[i] = fmaf(a4.z, wn4.z, an[i]);
      hr[i] = fmaf(h4.z, vr4.z, hr[i]); hz[i] = fmaf(h4.z, vz4.z, hz[i]); hn[i] = fmaf(h4.z, vn4.z, hn[i]);
      ar[i] = fmaf(a4.w, wr4.w, ar[i]); az[i] = fmaf(a4.w, wz4.w, az[i]); an[i] = fmaf(a4.w, wn4.w, an[i]);
      hr[i] = fmaf(h4.w, vr4.w, hr[i]); hz[i] = fmaf(h4.w, vz4.w, hz[i]); hn[i] = fmaf(h4.w, vn4.w, hn[i]);
    }
  }

#pragma unroll
  for (int i = 0; i < 4; ++i) {
    int node = node0 + i;
    if (node < n) {
      float r = 1.f / (1.f + __expf(-(ar[i] + hr[i] + Br)));
      float z = 1.f / (1.f + __expf(-(az[i] + hz[i] + Bz)));
      float nn = tanhf((an[i] + Bin) + r * (hn[i] + Bhn));
      xout[(size_t)node * HDIM + lane] = (1.f - z) * nn + z * xv[i];
    }
  }
}

// ---------------- per-graph mean pool of relu(x); batch sorted ----------------
__device__ __forceinline__ int lower_bound_i(const int* __restrict__ a, int n, int v) {
  int lo = 0, hi = n;
  while (lo < hi) {
    int mid = (lo + hi) >> 1;
    if (a[mid] < v) lo = mid + 1; else hi = mid;
  }
  return lo;
}

__global__ __launch_bounds__(256) void k_pool(const float* __restrict__ x,
                                              const int* __restrict__ batch,
                                              float* __restrict__ pooled,
                                              int n) {
  int g = blockIdx.x;
  int lo = lower_bound_i(batch, n, g);
  int hi = lower_bound_i(batch, n, g + 1);
  const int lane = threadIdx.x & 63;
  const int w = threadIdx.x >> 6;  // 0..3
  float acc = 0.f;
  for (int i = lo + w; i < hi; i += 4) {
    acc += fmaxf(x[i * HDIM + lane], 0.f);
  }
  __shared__ float red[4][HDIM];
  red[w][lane] = acc;
  __syncthreads();
  if (w == 0) {
    float s = red[0][lane] + red[1][lane] + red[2][lane] + red[3][lane];
    float cnt = (float)(hi - lo);
    pooled[g * HDIM + lane] = s / fmaxf(cnt, 1.f);
  }
}

// ---------------- head ----------------
__global__ __launch_bounds__(256) void k_head(const float* __restrict__ pooled,
                                              const float* __restrict__ lin1_w,
                                              const float* __restrict__ lin1_b,
                                              const float* __restrict__ lout_w,
                                              const float* __restrict__ lout_b,
                                              float* __restrict__ out, int G) {
  __shared__ float P[128 * HDIM];
  __shared__ float W1T[HDIM * HDIM];
  __shared__ float H1[128 * HDIM];
  for (int t = threadIdx.x; t < G * HDIM; t += 256) P[t] = pooled[t];
  for (int t = threadIdx.x; t < HDIM * HDIM; t += 256) {
    int j = t & 63, k = t >> 6;
    W1T[k * HDIM + j] = lin1_w[j * HDIM + k];
  }
  __syncthreads();
  for (int idx = threadIdx.x; idx < G * HDIM; idx += 256) {
    int g = idx >> 6, j = idx & 63;
    float acc = lin1_b[j];
#pragma unroll
    for (int k = 0; k < HDIM; ++k) acc = fmaf(P[g * HDIM + k], W1T[k * HDIM + j], acc);
    H1[idx] = fmaxf(acc, 0.f);
  }
  __syncthreads();
  for (int idx = threadIdx.x; idx < G * 2; idx += 256) {
    int g = idx >> 1, c = idx & 1;
    float acc = lout_b[c];
#pragma unroll
    for (int j = 0; j < HDIM; ++j) acc = fmaf(H1[g * HDIM + j], lout_w[c * HDIM + j], acc);
    out[idx] = acc;
  }
}

extern "C" void kernel_launch(void* const* d_in, const int* in_sizes, int n_in,
                              void* d_out, int out_size, void* d_ws, size_t ws_size,
                              hipStream_t stream) {
  const int* tokens   = (const int*)d_in[0];
  const int* edge_idx = (const int*)d_in[1];
  const int* batch    = (const int*)d_in[2];
  const float* emb    = (const float*)d_in[3];
  const float* ggnn_w = (const float*)d_in[4];
  const float* w_ih   = (const float*)d_in[5];
  const float* w_hh   = (const float*)d_in[6];
  const float* b_ih   = (const float*)d_in[7];
  const float* b_hh   = (const float*)d_in[8];
  const float* lin1_w = (const float*)d_in[9];
  const float* lin1_b = (const float*)d_in[10];
  const float* lout_w = (const float*)d_in[11];
  const float* lout_b = (const float*)d_in[12];

  const int N = in_sizes[0];
  const int E = in_sizes[1] / 2;
  const int G = out_size / 2;

  const int* srcs = edge_idx;
  const int* dsts = edge_idx + E;

  char* ws = (char*)d_ws;
  size_t off = 0;
  auto take = [&](size_t nbytes) -> char* {
    char* p = ws + off;
    off += (nbytes + 255) & ~(size_t)255;
    return p;
  };
  size_t rowBytes = (size_t)N * HDIM * sizeof(float);
  const int nb256 = (N + 255) / 256;
  float* xA     = (float*)take(rowBytes);
  float* xB     = (float*)take(rowBytes);
  float* pooled = (float*)take((size_t)G * HDIM * sizeof(float));
  float* whT_g  = (float*)take(HDIM * 3 * HDIM * sizeof(float));
  float* wc_g   = (float*)take((size_t)STEPS * HDIM * 3 * HDIM * sizeof(float));
  int* rowptr   = (int*)take((size_t)(N + 1) * sizeof(int));
  int* cursor   = (int*)take((size_t)N * sizeof(int));  // also used as deg
  int* bsum     = (int*)take((size_t)nb256 * sizeof(int));
  int* eidx     = (int*)take((size_t)E * sizeof(int));

  // --- one-time precompute: K-major float4 weights + CSR by dst ---
  {
    const int total = STEPS * HDIM * 3 * HDIM;
    k_prep<<<(total + 255) / 256, 256, 0, stream>>>(ggnn_w, w_ih, w_hh, wc_g, whT_g);
  }
  hipMemsetAsync(cursor, 0, (size_t)N * sizeof(int), stream);
  k_hist<<<(E + 255) / 256, 256, 0, stream>>>(dsts, cursor, E);
  k_scan1<<<nb256, 256, 0, stream>>>(cursor, bsum, N);
  k_scan2<<<1, 1024, 0, stream>>>(bsum, nb256);
  k_scan3<<<nb256, 256, 0, stream>>>(cursor, bsum, rowptr, cursor, N);
  k_fill<<<(E + 255) / 256, 256, 0, stream>>>(srcs, dsts, cursor, eidx, E);

  // --- embed ---
  k_embed<<<(N * HDIM + 255) / 256, 256, 0, stream>>>(tokens, emb, xA, N);

  // --- GGNN steps: fused gather+GRU, ping-pong x ---
  const int NG = (N + 3) / 4;
  const int fblocks = (NG + 7) / 8;
  float* xin = xA;
  float* xout = xB;
  for (int s = 0; s < STEPS; ++s) {
    k_fgru<<<fblocks, 512, 0, stream>>>(rowptr, eidx, (const float4*)xin, xin, xout,
                                        wc_g + (size_t)s * HDIM * 3 * HDIM,
                                        (const float4*)whT_g, b_ih, b_hh, N);
    float* tmp = xin; xin = xout; xout = tmp;
  }

  k_pool<<<G, 256, 0, stream>>>(xin, batch, pooled, N);
  k_head<<<1, 256, 0, stream>>>(pooled, lin1_w, lin1_b, lout_w, lout_b,
                                (float*)d_out, G);
}